// Round 12
// baseline (1117.993 us; speedup 1.0000x reference)
//
#include <hip/hip_runtime.h>
#include <hip/hip_bf16.h>
#include <hip/hip_cooperative_groups.h>

namespace cg = cooperative_groups;

#define NN 100000
#define NE 1600000
#define DD 128
#define NL 3
#define NG 512
#define CSRP (NE + 8 * NN)             // padded CSR capacity (ints) = 2.4M
#define BSHIFT 9                       // coarse bucket = 512 nodes
#define NBUCK2 ((NN + 511) / 512)      // 196 coarse buckets
#define ABLKS 512
#define ECHUNK (NE / ABLKS)            // 3125 edges per binA block (exact)
#define COOP_BLKS 1024
#define GSTRIDE (COOP_BLKS * 256)

typedef __attribute__((ext_vector_type(8))) short bf16x8;
typedef __attribute__((ext_vector_type(4))) float f32x4;

__device__ __forceinline__ unsigned short f2bf(float f) {
    union { float f; unsigned int u; } x; x.f = f;
    unsigned int r = x.u + 0x7FFFu + ((x.u >> 16) & 1u);
    return (unsigned short)(r >> 16);
}
__device__ __forceinline__ float bf2f(unsigned short u) {
    union { unsigned int u; float f; } x; x.u = ((unsigned int)u) << 16;
    return x.f;
}
__device__ __forceinline__ float bflo(unsigned int v) { return bf2f((unsigned short)(v & 0xffffu)); }
__device__ __forceinline__ float bfhi(unsigned int v) { return bf2f((unsigned short)(v >> 16)); }
__device__ __forceinline__ unsigned cvtpk(float lo, float hi) {
    unsigned r;
    asm("v_cvt_pk_bf16_f32 %0, %1, %2" : "=v"(r) : "v"(lo), "v"(hi));
    return r;
}

// ================= cooperative build: conv/prepw + full CSR chain =================
__global__ __launch_bounds__(256) void build_all(
    const float* __restrict__ x,
    unsigned short* __restrict__ h0,
    unsigned short* __restrict__ h1,
    const float* __restrict__ W1,
    const float* __restrict__ W2,
    unsigned short* __restrict__ wbf,
    const int* __restrict__ ei,
    int* __restrict__ bcnt,
    int* __restrict__ cboff,
    int* __restrict__ gpos,
    int* __restrict__ ebuf,
    int* __restrict__ rp,
    int* __restrict__ bsum,
    int* __restrict__ bbase,
    int* __restrict__ csr)
{
    cg::grid_group grid = cg::this_grid();
    __shared__ int smem[1024];   // 4 KB, aliased per phase
    const int tid = threadIdx.x;
    const int bid = blockIdx.x;
    const int gthread = bid * 256 + tid;

    // ---- P0: conv x->bf16 (+ zero pad rows of h0/h1) | prep_w | zero bcnt ----
    {
        const long long tot = (long long)(NN + 1) * DD / 4;
        for (long long t = gthread; t < tot; t += GSTRIDE) {
            long long base = t * 4;
            if (base < (long long)NN * DD) {
                float4 v = *reinterpret_cast<const float4*>(x + base);
                ushort4 p;
                p.x = f2bf(v.x); p.y = f2bf(v.y); p.z = f2bf(v.z); p.w = f2bf(v.w);
                *reinterpret_cast<ushort4*>(h0 + base) = p;
            } else {
                ushort4 z = {0, 0, 0, 0};
                *reinterpret_cast<ushort4*>(h0 + base) = z;
                *reinterpret_cast<ushort4*>(h1 + base) = z;
            }
        }
        for (int i = gthread; i < NL * 2 * DD * DD; i += GSTRIDE) {
            int k = i & 127;
            int n = (i >> 7) & 127;
            int w = (i >> 14) & 1;
            int l = i >> 15;
            const float* src = w ? W2 : W1;
            wbf[i] = f2bf(src[(l * DD + k) * DD + n]);
        }
        if (gthread < NBUCK2) bcnt[gthread] = 0;
    }
    grid.sync();

    // ---- P1: bcount (block-staged coarse histogram) ----
    if (bid < ABLKS) {
        int* hist = smem;
        for (int i = tid; i < NBUCK2; i += 256) hist[i] = 0;
        __syncthreads();
        int e0 = bid * ECHUNK;
        for (int i = tid; i < ECHUNK; i += 256)
            atomicAdd(&hist[ei[NE + e0 + i] >> BSHIFT], 1);
        __syncthreads();
        for (int i = tid; i < NBUCK2; i += 256) {
            int h = hist[i];
            if (h) atomicAdd(&bcnt[i], h);
        }
    }
    grid.sync();

    // ---- P2: bscan (block 0): exclusive scan bcnt -> cboff; zero gpos ----
    if (bid == 0) {
        int* s = smem;
        int sum = (tid < NBUCK2) ? bcnt[tid] : 0;
        s[tid] = sum;
        __syncthreads();
        for (int o = 1; o < 256; o <<= 1) {
            int t2 = (tid >= o) ? s[tid - o] : 0;
            __syncthreads();
            s[tid] += t2;
            __syncthreads();
        }
        if (tid < NBUCK2) {
            cboff[tid] = s[tid] - sum;
            gpos[tid] = 0;
        }
        if (tid == 0) cboff[NBUCK2] = NE;
    }
    grid.sync();

    // ---- P3: binA (block-staged binning into ebuf) ----
    if (bid < ABLKS) {
        int* hist = smem;
        int* sbase = smem + 256;
        for (int i = tid; i < NBUCK2; i += 256) hist[i] = 0;
        __syncthreads();
        int e0 = bid * ECHUNK;
        for (int i = tid; i < ECHUNK; i += 256)
            atomicAdd(&hist[ei[NE + e0 + i] >> BSHIFT], 1);
        __syncthreads();
        for (int i = tid; i < NBUCK2; i += 256) {
            int h = hist[i];
            sbase[i] = (h > 0) ? atomicAdd(&gpos[i], h) : 0;
            hist[i] = 0;    // reuse as cursor
        }
        __syncthreads();
        for (int i = tid; i < ECHUNK; i += 256) {
            int s2 = ei[e0 + i];
            int d = ei[NE + e0 + i];
            int b = d >> BSHIFT;
            int pos = atomicAdd(&hist[b], 1);
            ebuf[cboff[b] + sbase[b] + pos] = s2 | ((d & 511) << 17);
        }
    }
    grid.sync();

    // ---- P4: bpre (per bucket: degree count, padded local prefix -> rp) ----
    if (bid < NBUCK2) {
        int* lcnt = smem;        // 512
        int* s = smem + 512;     // 256
        lcnt[tid] = 0;
        lcnt[tid + 256] = 0;
        __syncthreads();
        int st = cboff[bid], en = cboff[bid + 1];
        for (int i = st + tid; i < en; i += 256)
            atomicAdd(&lcnt[ebuf[i] >> 17], 1);
        __syncthreads();
        int d0 = (lcnt[2 * tid] + 7) & ~7;
        int d1 = (lcnt[2 * tid + 1] + 7) & ~7;
        int ps = d0 + d1;
        s[tid] = ps;
        __syncthreads();
        for (int o = 1; o < 256; o <<= 1) {
            int t2 = (tid >= o) ? s[tid - o] : 0;
            __syncthreads();
            s[tid] += t2;
            __syncthreads();
        }
        int base = s[tid] - ps;
        int node0 = (bid << BSHIFT) + 2 * tid;
        if (node0 < NN) rp[node0] = base;
        if (node0 + 1 < NN) rp[node0 + 1] = base + d0;
        if (tid == 255) bsum[bid] = s[255];
    }
    grid.sync();

    // ---- P5: bscan2 (block 0): scan bsum -> bbase; rp[NN] = total ----
    if (bid == 0) {
        int* s = smem;
        int sum = (tid < NBUCK2) ? bsum[tid] : 0;
        s[tid] = sum;
        __syncthreads();
        for (int o = 1; o < 256; o <<= 1) {
            int t2 = (tid >= o) ? s[tid - o] : 0;
            __syncthreads();
            s[tid] += t2;
            __syncthreads();
        }
        if (tid < NBUCK2) bbase[tid] = s[tid] - sum;
        if (tid == 255) rp[NN] = s[255];
    }
    grid.sync();

    // ---- P6: binB2 (finalize rp, place edges, write pads) ----
    if (bid < NBUCK2) {
        int* rpl = smem;         // 512
        int* lcnt = smem + 512;  // 512
        int bb = bbase[bid];
        for (int i = tid; i < 512; i += 256) {
            int node = (bid << BSHIFT) + i;
            int v = 0;
            if (node < NN) {
                v = rp[node] + bb;
                rp[node] = v;
            }
            rpl[i] = v;
            lcnt[i] = 0;
        }
        __syncthreads();
        int st = cboff[bid], en = cboff[bid + 1];
        for (int i = st + tid; i < en; i += 256) {
            int v = ebuf[i];
            int dl = v >> 17;
            int pos = atomicAdd(&lcnt[dl], 1);
            csr[rpl[dl] + pos] = v & 0x1FFFF;
        }
        __syncthreads();
        for (int i = tid; i < 512; i += 256) {
            int node = (bid << BSHIFT) + i;
            if (node >= NN) continue;
            int d = lcnt[i];
            int pd = (d + 7) & ~7;
            int base = rpl[i];
            for (int j = d; j < pd; ++j) csr[base + j] = NN;
        }
    }
}

// ---------------- fused layer: gather-agg + MLP + BN ----------------
__global__ __launch_bounds__(256) void layer_fused(
    const unsigned short* __restrict__ hin,   // (NN+1) rows, row NN = zeros
    const int* __restrict__ rp,               // padded row ptr (8-aligned)
    const int* __restrict__ csr,              // padded neighbor lists
    const unsigned short* __restrict__ w1t,   // [n][k] bf16
    const unsigned short* __restrict__ w2t,   // [n][k] bf16
    const float* __restrict__ b1,
    const float* __restrict__ b2,
    const float* __restrict__ gamma,
    const float* __restrict__ beta,
    const float* __restrict__ rmean,
    const float* __restrict__ rvar,
    const float* __restrict__ epsv,
    unsigned short* __restrict__ hout)
{
    __shared__ unsigned short z_lds[16 * 136];   // 4.35 KB
    const int tid = threadIdx.x;
    const int lane = tid & 63;
    const int wave = tid >> 6;
    const int gid = lane >> 4;        // group 0..3, owns one row
    const int lg = lane & 15;         // 16B feature slice within group
    const int row0 = blockIdx.x * 16;
    const float epl = 1.0f + epsv[0];
    const size_t lgo = (size_t)lg * 8;

#define ACC8(v) do { \
    acc[0] += bflo((v).x); acc[1] += bfhi((v).x); \
    acc[2] += bflo((v).y); acc[3] += bfhi((v).y); \
    acc[4] += bflo((v).z); acc[5] += bfhi((v).z); \
    acc[6] += bflo((v).w); acc[7] += bfhi((v).w); } while (0)

    // Phase 1: gather-aggregate; group g of wave w owns row w*4+g
    const int rbase = row0 + (wave << 2);
    int pv = (lane < 5) ? rp[rbase + lane] : 0;   // 5 rowptrs
    const int st = __shfl(pv, gid);
    const int en = __shfl(pv, gid + 1);
    const int myrow = rbase + gid;

    float acc[8];
    {
        uint4 sv = *reinterpret_cast<const uint4*>(hin + (size_t)myrow * DD + lgo);
        acc[0] = epl * bflo(sv.x); acc[1] = epl * bfhi(sv.x);
        acc[2] = epl * bflo(sv.y); acc[3] = epl * bfhi(sv.y);
        acc[4] = epl * bflo(sv.z); acc[5] = epl * bfhi(sv.z);
        acc[6] = epl * bflo(sv.w); acc[7] = epl * bfhi(sv.w);
    }
    for (int c0 = st; c0 < en; c0 += 8) {
        int4 idA = *reinterpret_cast<const int4*>(csr + c0);
        int4 idB = *reinterpret_cast<const int4*>(csr + c0 + 4);
        uint4 v0 = *reinterpret_cast<const uint4*>(hin + (size_t)idA.x * DD + lgo);
        uint4 v1 = *reinterpret_cast<const uint4*>(hin + (size_t)idA.y * DD + lgo);
        uint4 v2 = *reinterpret_cast<const uint4*>(hin + (size_t)idA.z * DD + lgo);
        uint4 v3 = *reinterpret_cast<const uint4*>(hin + (size_t)idA.w * DD + lgo);
        uint4 v4 = *reinterpret_cast<const uint4*>(hin + (size_t)idB.x * DD + lgo);
        uint4 v5 = *reinterpret_cast<const uint4*>(hin + (size_t)idB.y * DD + lgo);
        uint4 v6 = *reinterpret_cast<const uint4*>(hin + (size_t)idB.z * DD + lgo);
        uint4 v7 = *reinterpret_cast<const uint4*>(hin + (size_t)idB.w * DD + lgo);
        ACC8(v0); ACC8(v1); ACC8(v2); ACC8(v3);
        ACC8(v4); ACC8(v5); ACC8(v6); ACC8(v7);
    }
    {
        uint4 pk;
        pk.x = cvtpk(acc[0], acc[1]);
        pk.y = cvtpk(acc[2], acc[3]);
        pk.z = cvtpk(acc[4], acc[5]);
        pk.w = cvtpk(acc[6], acc[7]);
        *reinterpret_cast<uint4*>(&z_lds[((wave << 2) + gid) * 136 + lg * 8]) = pk;
    }
    __syncthreads();

    const int l15 = lane & 15;
    const int kq = lane >> 4;
    const int colbase = wave << 5;     // 32-col slice per wave

    // afr reads of z tile, then barrier (lets epi1 overlap others' MFMA1)
    bf16x8 afr[4];
    #pragma unroll
    for (int kk = 0; kk < 4; ++kk)
        afr[kk] = *reinterpret_cast<const bf16x8*>(&z_lds[l15 * 136 + kk * 32 + kq * 8]);
    __syncthreads();

    // Matmul 1
    f32x4 acc4[2];
    #pragma unroll
    for (int nt = 0; nt < 2; ++nt) acc4[nt] = (f32x4){0.f, 0.f, 0.f, 0.f};
    #pragma unroll
    for (int nt = 0; nt < 2; ++nt) {
        #pragma unroll
        for (int kk = 0; kk < 4; ++kk) {
            bf16x8 bfr = *reinterpret_cast<const bf16x8*>(
                w1t + (colbase + nt * 16 + l15) * DD + kk * 32 + kq * 8);
            acc4[nt] = __builtin_amdgcn_mfma_f32_16x16x32_bf16(afr[kk], bfr, acc4[nt], 0, 0, 0);
        }
    }

    // Epilogue 1: bias+relu, z1 -> z_lds (own 32-col slice, rows 0..15)
    #pragma unroll
    for (int nt = 0; nt < 2; ++nt) {
        int col = colbase + nt * 16 + l15;
        float bv = b1[col];
        #pragma unroll
        for (int r = 0; r < 4; ++r) {
            int zr = kq * 4 + r;
            float v = acc4[nt][r] + bv;
            v = v > 0.f ? v : 0.f;
            z_lds[zr * 136 + col] = f2bf(v);
        }
    }
    __syncthreads();

    // Matmul 2
    #pragma unroll
    for (int kk = 0; kk < 4; ++kk)
        afr[kk] = *reinterpret_cast<const bf16x8*>(&z_lds[l15 * 136 + kk * 32 + kq * 8]);
    #pragma unroll
    for (int nt = 0; nt < 2; ++nt) acc4[nt] = (f32x4){0.f, 0.f, 0.f, 0.f};
    #pragma unroll
    for (int nt = 0; nt < 2; ++nt) {
        #pragma unroll
        for (int kk = 0; kk < 4; ++kk) {
            bf16x8 bfr = *reinterpret_cast<const bf16x8*>(
                w2t + (colbase + nt * 16 + l15) * DD + kk * 32 + kq * 8);
            acc4[nt] = __builtin_amdgcn_mfma_f32_16x16x32_bf16(afr[kk], bfr, acc4[nt], 0, 0, 0);
        }
    }

    // Epilogue 2: bias+relu+BN -> hout (bf16); rows always < NN (no tail)
    #pragma unroll
    for (int nt = 0; nt < 2; ++nt) {
        int col = colbase + nt * 16 + l15;
        float bv = b2[col];
        float ga = gamma[col];
        float be = beta[col];
        float mu = rmean[col];
        float inv = rsqrtf(rvar[col] + 1e-5f);
        #pragma unroll
        for (int r = 0; r < 4; ++r) {
            int zr = kq * 4 + r;
            float v = acc4[nt][r] + bv;
            v = v > 0.f ? v : 0.f;
            v = (v - mu) * inv * ga + be;
            hout[(size_t)(row0 + zr) * DD + col] = f2bf(v);
        }
    }
#undef ACC8
}

// ---------------- pool (sorted batch -> segment sums) + final linear ----------------
__global__ __launch_bounds__(256) void pool_final(const unsigned short* __restrict__ h,
                                                  const int* __restrict__ batch,
                                                  const float* __restrict__ W,
                                                  const float* __restrict__ b,
                                                  float* __restrict__ out) {
    int g = blockIdx.x;           // one block per graph
    int t = threadIdx.x;
    int c2 = t & 63;              // col pair 2*c2, 2*c2+1
    int qu = t >> 6;              // row strand 0..3

    int lo = 0, hi = NN;
    while (lo < hi) { int mid = (lo + hi) >> 1; if (batch[mid] < g) lo = mid + 1; else hi = mid; }
    int start = lo;
    hi = NN;
    while (lo < hi) { int mid = (lo + hi) >> 1; if (batch[mid] < g + 1) lo = mid + 1; else hi = mid; }
    int end = lo;

    float ax = 0.f, ay = 0.f;
    for (int i = start + qu; i < end; i += 4) {
        unsigned u = *reinterpret_cast<const unsigned*>(h + (size_t)i * DD + c2 * 2);
        ax += bflo(u); ay += bfhi(u);
    }

    __shared__ float ps[4][DD];
    ps[qu][c2 * 2] = ax;
    ps[qu][c2 * 2 + 1] = ay;
    __syncthreads();
    if (t < DD) {
        float inv = 1.0f / fmaxf((float)(end - start), 1.0f);
        ps[0][t] = (ps[0][t] + ps[1][t] + ps[2][t] + ps[3][t]) * inv;
    }
    __syncthreads();
    if (t < DD) {
        float o = b[t];
        #pragma unroll 8
        for (int k = 0; k < DD; ++k)
            o += ps[0][k] * W[k * DD + t];
        out[(size_t)g * DD + t] = fmaxf(o, 0.f);
    }
}

extern "C" void kernel_launch(void* const* d_in, const int* in_sizes, int n_in,
                              void* d_out, int out_size, void* d_ws, size_t ws_size,
                              hipStream_t stream) {
    const float* x     = (const float*)d_in[0];
    const int*   ei    = (const int*)d_in[1];
    const int*   batch = (const int*)d_in[2];
    const float* W1    = (const float*)d_in[3];
    const float* b1    = (const float*)d_in[4];
    const float* W2    = (const float*)d_in[5];
    const float* b2    = (const float*)d_in[6];
    const float* gamma = (const float*)d_in[7];
    const float* beta  = (const float*)d_in[8];
    const float* rmean = (const float*)d_in[9];
    const float* rvar  = (const float*)d_in[10];
    const float* eps   = (const float*)d_in[11];
    const float* lin1W = (const float*)d_in[12];
    const float* lin1b = (const float*)d_in[13];
    float* out = (float*)d_out;

    char* ws = (char*)d_ws;
    size_t off = 0;
    auto alloc = [&](size_t bytes) {
        void* p = ws + off;
        off = (off + bytes + 255) & ~(size_t)255;
        return p;
    };
    unsigned short* h0  = (unsigned short*)alloc((size_t)(NN + 1) * DD * 2);
    unsigned short* h1  = (unsigned short*)alloc((size_t)(NN + 1) * DD * 2);
    int* rp     = (int*)alloc((size_t)(NN + 1) * 4);
    int* bcnt   = (int*)alloc((size_t)NBUCK2 * 4);
    int* cboff  = (int*)alloc((size_t)(NBUCK2 + 1) * 4);
    int* gpos   = (int*)alloc((size_t)NBUCK2 * 4);
    int* bsum   = (int*)alloc((size_t)NBUCK2 * 4);
    int* bbase  = (int*)alloc((size_t)NBUCK2 * 4);
    int* csr    = (int*)alloc((size_t)CSRP * 4);
    int* ebuf   = (int*)alloc((size_t)NE * 4);
    unsigned short* wbf = (unsigned short*)alloc((size_t)NL * 2 * DD * DD * 2);

    // one cooperative dispatch replaces the whole init + CSR chain
    {
        void* args[] = {
            (void*)&x, (void*)&h0, (void*)&h1, (void*)&W1, (void*)&W2, (void*)&wbf,
            (void*)&ei, (void*)&bcnt, (void*)&cboff, (void*)&gpos, (void*)&ebuf,
            (void*)&rp, (void*)&bsum, (void*)&bbase, (void*)&csr
        };
        hipLaunchCooperativeKernel((void*)build_all, dim3(COOP_BLKS), dim3(256),
                                   args, 0, stream);
    }

    const int lgrid = NN / 16;   // 6250, exact
    layer_fused<<<lgrid, 256, 0, stream>>>(
        h0, rp, csr, wbf + 0 * DD * DD, wbf + 1 * DD * DD,
        b1 + 0 * DD, b2 + 0 * DD, gamma + 0 * DD, beta + 0 * DD,
        rmean + 0 * DD, rvar + 0 * DD, eps + 0, h1);
    layer_fused<<<lgrid, 256, 0, stream>>>(
        h1, rp, csr, wbf + 2 * DD * DD, wbf + 3 * DD * DD,
        b1 + 1 * DD, b2 + 1 * DD, gamma + 1 * DD, beta + 1 * DD,
        rmean + 1 * DD, rvar + 1 * DD, eps + 1, h0);
    layer_fused<<<lgrid, 256, 0, stream>>>(
        h0, rp, csr, wbf + 4 * DD * DD, wbf + 5 * DD * DD,
        b1 + 2 * DD, b2 + 2 * DD, gamma + 2 * DD, beta + 2 * DD,
        rmean + 2 * DD, rvar + 2 * DD, eps + 2, h1);

    pool_final<<<NG, 256, 0, stream>>>(h1, batch, lin1W, lin1b, out);
}

// Round 13
// 456.411 us; speedup vs baseline: 2.4495x; 2.4495x over previous
//
#include <hip/hip_runtime.h>
#include <hip/hip_bf16.h>

#define NN 100000
#define NE 1600000
#define DD 128
#define NL 3
#define NG 512
#define CSRP (NE + 8 * NN)             // padded CSR capacity (ints) = 2.4M
#define BSHIFT 9                       // coarse bucket = 512 nodes
#define NBUCK2 ((NN + 511) / 512)      // 196 coarse buckets
#define ABLKS 512
#define ECHUNK (NE / ABLKS)            // 3125 edges per binA block (exact)

// fused init kernel block ranges (256 threads each)
#define CONV_BLKS 12501                // (NN+1)*DD/4 threads
#define PREPW_BLKS 384                 // NL*2*DD*DD/256
#define INIT_BLKS (CONV_BLKS + PREPW_BLKS + ABLKS)

typedef __attribute__((ext_vector_type(8))) short bf16x8;
typedef __attribute__((ext_vector_type(4))) float f32x4;

__device__ __forceinline__ unsigned short f2bf(float f) {
    union { float f; unsigned int u; } x; x.f = f;
    unsigned int r = x.u + 0x7FFFu + ((x.u >> 16) & 1u);
    return (unsigned short)(r >> 16);
}
__device__ __forceinline__ float bf2f(unsigned short u) {
    union { unsigned int u; float f; } x; x.u = ((unsigned int)u) << 16;
    return x.f;
}
__device__ __forceinline__ float bflo(unsigned int v) { return bf2f((unsigned short)(v & 0xffffu)); }
__device__ __forceinline__ float bfhi(unsigned int v) { return bf2f((unsigned short)(v >> 16)); }
__device__ __forceinline__ unsigned cvtpk(float lo, float hi) {
    unsigned r;
    asm("v_cvt_pk_bf16_f32 %0, %1, %2" : "=v"(r) : "v"(lo), "v"(hi));
    return r;
}

// -------- fused init: conv_x | prep_w | per-block bucket histogram (pure writes) --------
__global__ __launch_bounds__(256) void init_all(const float* __restrict__ x,
                                                unsigned short* __restrict__ h0,
                                                unsigned short* __restrict__ h1,
                                                const float* __restrict__ W1,
                                                const float* __restrict__ W2,
                                                unsigned short* __restrict__ wbf,
                                                const int* __restrict__ ei,
                                                int* __restrict__ blkhist) {
    int bb = blockIdx.x;
    int tid = threadIdx.x;
    if (bb < CONV_BLKS) {
        long long t = (long long)bb * 256 + tid;
        long long base = t * 4;
        if (base < (long long)NN * DD) {
            float4 v = *reinterpret_cast<const float4*>(x + base);
            ushort4 p;
            p.x = f2bf(v.x); p.y = f2bf(v.y); p.z = f2bf(v.z); p.w = f2bf(v.w);
            *reinterpret_cast<ushort4*>(h0 + base) = p;
        } else if (base < (long long)(NN + 1) * DD) {
            ushort4 z = {0, 0, 0, 0};
            *reinterpret_cast<ushort4*>(h0 + base) = z;
            *reinterpret_cast<ushort4*>(h1 + base) = z;
        }
        return;
    }
    bb -= CONV_BLKS;
    if (bb < PREPW_BLKS) {
        int idx = bb * 256 + tid;                    // < NL*2*DD*DD
        int k = idx & 127;
        int n = (idx >> 7) & 127;
        int w = (idx >> 14) & 1;
        int l = idx >> 15;
        const float* src = w ? W2 : W1;
        wbf[idx] = f2bf(src[(l * DD + k) * DD + n]);
        return;
    }
    bb -= PREPW_BLKS;                                // 0..ABLKS-1: histogram chunk bb
    {
        __shared__ int hist[NBUCK2];
        for (int i = tid; i < NBUCK2; i += 256) hist[i] = 0;
        __syncthreads();
        int e0 = bb * ECHUNK;
        for (int i = tid; i < ECHUNK; i += 256)
            atomicAdd(&hist[ei[NE + e0 + i] >> BSHIFT], 1);
        __syncthreads();
        for (int i = tid; i < NBUCK2; i += 256)
            blkhist[i * ABLKS + bb] = hist[i];       // pure write, no global atomic
    }
}

// per bucket: exclusive scan over its 512 block-counts (in place) + total -> bsumb
__global__ __launch_bounds__(256) void scanA(int* __restrict__ blkhist,
                                             int* __restrict__ bsumb) {
    __shared__ int s[256];
    int b = blockIdx.x;
    int tid = threadIdx.x;
    int* row = blkhist + (size_t)b * ABLKS;
    int v0 = row[2 * tid];
    int v1 = row[2 * tid + 1];
    int ps = v0 + v1;
    s[tid] = ps;
    __syncthreads();
    for (int o = 1; o < 256; o <<= 1) {
        int t2 = (tid >= o) ? s[tid - o] : 0;
        __syncthreads();
        s[tid] += t2;
        __syncthreads();
    }
    int base = s[tid] - ps;
    row[2 * tid] = base;
    row[2 * tid + 1] = base + v0;
    if (tid == 255) bsumb[b] = s[255];
}

// single block: exclusive scan bsumb -> cboff
__global__ __launch_bounds__(256) void scanB(const int* __restrict__ bsumb,
                                             int* __restrict__ cboff) {
    __shared__ int s[256];
    int tid = threadIdx.x;
    int sum = (tid < NBUCK2) ? bsumb[tid] : 0;
    s[tid] = sum;
    __syncthreads();
    for (int o = 1; o < 256; o <<= 1) {
        int t2 = (tid >= o) ? s[tid - o] : 0;
        __syncthreads();
        s[tid] += t2;
        __syncthreads();
    }
    if (tid < NBUCK2) cboff[tid] = s[tid] - sum;
    if (tid == 0) cboff[NBUCK2] = NE;
}

// single-pass scatter: base = cboff[b] + blkhist[b][blk], LDS cursors
__global__ __launch_bounds__(256) void binA2(const int* __restrict__ ei,
                                             const int* __restrict__ cboff,
                                             const int* __restrict__ blkhist,
                                             int* __restrict__ ebuf) {
    __shared__ int lbase[NBUCK2];
    __shared__ int cur[NBUCK2];
    int tid = threadIdx.x;
    int bid = blockIdx.x;
    if (tid < NBUCK2) {
        lbase[tid] = cboff[tid] + blkhist[tid * ABLKS + bid];
        cur[tid] = 0;
    }
    __syncthreads();
    int e0 = bid * ECHUNK;
    for (int i = tid; i < ECHUNK; i += 256) {
        int s2 = ei[e0 + i];
        int d = ei[NE + e0 + i];
        int b = d >> BSHIFT;
        int pos = atomicAdd(&cur[b], 1);
        ebuf[lbase[b] + pos] = s2 | ((d & 511) << 17);
    }
}

// per bucket: count degrees from own ebuf segment (LDS), padded local prefix
// -> rp (bucket-local), bucket padded total -> bsum
__global__ __launch_bounds__(256) void bpre(const int* __restrict__ ebuf,
                                            const int* __restrict__ cboff,
                                            int* __restrict__ rp,
                                            int* __restrict__ bsum) {
    __shared__ int lcnt[512];
    __shared__ int s[256];
    int b = blockIdx.x;
    int tid = threadIdx.x;
    lcnt[tid] = 0;
    lcnt[tid + 256] = 0;
    __syncthreads();
    int st = cboff[b], en = cboff[b + 1];
    for (int i = st + tid; i < en; i += 256)
        atomicAdd(&lcnt[ebuf[i] >> 17], 1);
    __syncthreads();
    int d0 = (lcnt[2 * tid] + 7) & ~7;
    int d1 = (lcnt[2 * tid + 1] + 7) & ~7;
    int ps = d0 + d1;
    s[tid] = ps;
    __syncthreads();
    for (int o = 1; o < 256; o <<= 1) {
        int t2 = (tid >= o) ? s[tid - o] : 0;
        __syncthreads();
        s[tid] += t2;
        __syncthreads();
    }
    int base = s[tid] - ps;   // exclusive over pairs
    int node0 = (b << BSHIFT) + 2 * tid;
    if (node0 < NN) rp[node0] = base;
    if (node0 + 1 < NN) rp[node0 + 1] = base + d0;
    if (tid == 255) bsum[b] = s[255];
}

__global__ __launch_bounds__(256) void bscan2(const int* __restrict__ bsum,
                                              int* __restrict__ bbase,
                                              int* __restrict__ rp) {
    __shared__ int s[256];
    int tid = threadIdx.x;
    int sum = (tid < NBUCK2) ? bsum[tid] : 0;
    s[tid] = sum;
    __syncthreads();
    for (int o = 1; o < 256; o <<= 1) {
        int t2 = (tid >= o) ? s[tid - o] : 0;
        __syncthreads();
        s[tid] += t2;
        __syncthreads();
    }
    if (tid < NBUCK2) bbase[tid] = s[tid] - sum;
    if (tid == 255) rp[NN] = s[255];
}

// per bucket: finalize rp (+= bbase), place edges via LDS cursors, write pads
__global__ __launch_bounds__(256) void binB2(const int* __restrict__ ebuf,
                                             const int* __restrict__ cboff,
                                             const int* __restrict__ bbase,
                                             int* __restrict__ rp,
                                             int* __restrict__ csr) {
    __shared__ int rpl[512];
    __shared__ int lcnt[512];
    int b = blockIdx.x;
    int tid = threadIdx.x;
    int bb = bbase[b];
    for (int i = tid; i < 512; i += 256) {
        int node = (b << BSHIFT) + i;
        int v = 0;
        if (node < NN) {
            v = rp[node] + bb;
            rp[node] = v;
        }
        rpl[i] = v;
        lcnt[i] = 0;
    }
    __syncthreads();
    int st = cboff[b], en = cboff[b + 1];
    for (int i = st + tid; i < en; i += 256) {
        int v = ebuf[i];
        int dl = v >> 17;
        int pos = atomicAdd(&lcnt[dl], 1);
        csr[rpl[dl] + pos] = v & 0x1FFFF;
    }
    __syncthreads();
    for (int i = tid; i < 512; i += 256) {
        int node = (b << BSHIFT) + i;
        if (node >= NN) continue;
        int d = lcnt[i];
        int pd = (d + 7) & ~7;
        int base = rpl[i];
        for (int j = d; j < pd; ++j) csr[base + j] = NN;
    }
}

// ---------------- fused layer: gather-agg + MLP + BN ----------------
__global__ __launch_bounds__(256) void layer_fused(
    const unsigned short* __restrict__ hin,   // (NN+1) rows, row NN = zeros
    const int* __restrict__ rp,               // padded row ptr (8-aligned)
    const int* __restrict__ csr,              // padded neighbor lists
    const unsigned short* __restrict__ w1t,   // [n][k] bf16
    const unsigned short* __restrict__ w2t,   // [n][k] bf16
    const float* __restrict__ b1,
    const float* __restrict__ b2,
    const float* __restrict__ gamma,
    const float* __restrict__ beta,
    const float* __restrict__ rmean,
    const float* __restrict__ rvar,
    const float* __restrict__ epsv,
    unsigned short* __restrict__ hout)
{
    __shared__ unsigned short z_lds[16 * 136];   // 4.35 KB
    const int tid = threadIdx.x;
    const int lane = tid & 63;
    const int wave = tid >> 6;
    const int gid = lane >> 4;        // group 0..3, owns one row
    const int lg = lane & 15;         // 16B feature slice within group
    const int row0 = blockIdx.x * 16;
    const float epl = 1.0f + epsv[0];
    const size_t lgo = (size_t)lg * 8;

#define ACC8(v) do { \
    acc[0] += bflo((v).x); acc[1] += bfhi((v).x); \
    acc[2] += bflo((v).y); acc[3] += bfhi((v).y); \
    acc[4] += bflo((v).z); acc[5] += bfhi((v).z); \
    acc[6] += bflo((v).w); acc[7] += bfhi((v).w); } while (0)

    // Phase 1: gather-aggregate; group g of wave w owns row w*4+g
    const int rbase = row0 + (wave << 2);
    int pv = (lane < 5) ? rp[rbase + lane] : 0;   // 5 rowptrs
    const int st = __shfl(pv, gid);
    const int en = __shfl(pv, gid + 1);
    const int myrow = rbase + gid;

    float acc[8];
    {
        uint4 sv = *reinterpret_cast<const uint4*>(hin + (size_t)myrow * DD + lgo);
        acc[0] = epl * bflo(sv.x); acc[1] = epl * bfhi(sv.x);
        acc[2] = epl * bflo(sv.y); acc[3] = epl * bfhi(sv.y);
        acc[4] = epl * bflo(sv.z); acc[5] = epl * bfhi(sv.z);
        acc[6] = epl * bflo(sv.w); acc[7] = epl * bfhi(sv.w);
    }
    for (int c0 = st; c0 < en; c0 += 8) {
        int4 idA = *reinterpret_cast<const int4*>(csr + c0);
        int4 idB = *reinterpret_cast<const int4*>(csr + c0 + 4);
        uint4 v0 = *reinterpret_cast<const uint4*>(hin + (size_t)idA.x * DD + lgo);
        uint4 v1 = *reinterpret_cast<const uint4*>(hin + (size_t)idA.y * DD + lgo);
        uint4 v2 = *reinterpret_cast<const uint4*>(hin + (size_t)idA.z * DD + lgo);
        uint4 v3 = *reinterpret_cast<const uint4*>(hin + (size_t)idA.w * DD + lgo);
        uint4 v4 = *reinterpret_cast<const uint4*>(hin + (size_t)idB.x * DD + lgo);
        uint4 v5 = *reinterpret_cast<const uint4*>(hin + (size_t)idB.y * DD + lgo);
        uint4 v6 = *reinterpret_cast<const uint4*>(hin + (size_t)idB.z * DD + lgo);
        uint4 v7 = *reinterpret_cast<const uint4*>(hin + (size_t)idB.w * DD + lgo);
        ACC8(v0); ACC8(v1); ACC8(v2); ACC8(v3);
        ACC8(v4); ACC8(v5); ACC8(v6); ACC8(v7);
    }
    {
        uint4 pk;
        pk.x = cvtpk(acc[0], acc[1]);
        pk.y = cvtpk(acc[2], acc[3]);
        pk.z = cvtpk(acc[4], acc[5]);
        pk.w = cvtpk(acc[6], acc[7]);
        *reinterpret_cast<uint4*>(&z_lds[((wave << 2) + gid) * 136 + lg * 8]) = pk;
    }
    __syncthreads();

    const int l15 = lane & 15;
    const int kq = lane >> 4;
    const int colbase = wave << 5;     // 32-col slice per wave

    // afr reads of z tile, then barrier (lets epi1 overlap others' MFMA1)
    bf16x8 afr[4];
    #pragma unroll
    for (int kk = 0; kk < 4; ++kk)
        afr[kk] = *reinterpret_cast<const bf16x8*>(&z_lds[l15 * 136 + kk * 32 + kq * 8]);
    __syncthreads();

    // Matmul 1
    f32x4 acc4[2];
    #pragma unroll
    for (int nt = 0; nt < 2; ++nt) acc4[nt] = (f32x4){0.f, 0.f, 0.f, 0.f};
    #pragma unroll
    for (int nt = 0; nt < 2; ++nt) {
        #pragma unroll
        for (int kk = 0; kk < 4; ++kk) {
            bf16x8 bfr = *reinterpret_cast<const bf16x8*>(
                w1t + (colbase + nt * 16 + l15) * DD + kk * 32 + kq * 8);
            acc4[nt] = __builtin_amdgcn_mfma_f32_16x16x32_bf16(afr[kk], bfr, acc4[nt], 0, 0, 0);
        }
    }

    // Epilogue 1: bias+relu, z1 -> z_lds (own 32-col slice, rows 0..15)
    #pragma unroll
    for (int nt = 0; nt < 2; ++nt) {
        int col = colbase + nt * 16 + l15;
        float bv = b1[col];
        #pragma unroll
        for (int r = 0; r < 4; ++r) {
            int zr = kq * 4 + r;
            float v = acc4[nt][r] + bv;
            v = v > 0.f ? v : 0.f;
            z_lds[zr * 136 + col] = f2bf(v);
        }
    }
    __syncthreads();

    // Matmul 2
    #pragma unroll
    for (int kk = 0; kk < 4; ++kk)
        afr[kk] = *reinterpret_cast<const bf16x8*>(&z_lds[l15 * 136 + kk * 32 + kq * 8]);
    #pragma unroll
    for (int nt = 0; nt < 2; ++nt) acc4[nt] = (f32x4){0.f, 0.f, 0.f, 0.f};
    #pragma unroll
    for (int nt = 0; nt < 2; ++nt) {
        #pragma unroll
        for (int kk = 0; kk < 4; ++kk) {
            bf16x8 bfr = *reinterpret_cast<const bf16x8*>(
                w2t + (colbase + nt * 16 + l15) * DD + kk * 32 + kq * 8);
            acc4[nt] = __builtin_amdgcn_mfma_f32_16x16x32_bf16(afr[kk], bfr, acc4[nt], 0, 0, 0);
        }
    }

    // Epilogue 2: bias+relu+BN -> hout (bf16); rows always < NN (no tail)
    #pragma unroll
    for (int nt = 0; nt < 2; ++nt) {
        int col = colbase + nt * 16 + l15;
        float bv = b2[col];
        float ga = gamma[col];
        float be = beta[col];
        float mu = rmean[col];
        float inv = rsqrtf(rvar[col] + 1e-5f);
        #pragma unroll
        for (int r = 0; r < 4; ++r) {
            int zr = kq * 4 + r;
            float v = acc4[nt][r] + bv;
            v = v > 0.f ? v : 0.f;
            v = (v - mu) * inv * ga + be;
            hout[(size_t)(row0 + zr) * DD + col] = f2bf(v);
        }
    }
#undef ACC8
}

// ---------------- pool (sorted batch -> segment sums) + final linear ----------------
__global__ __launch_bounds__(256) void pool_final(const unsigned short* __restrict__ h,
                                                  const int* __restrict__ batch,
                                                  const float* __restrict__ W,
                                                  const float* __restrict__ b,
                                                  float* __restrict__ out) {
    int g = blockIdx.x;           // one block per graph
    int t = threadIdx.x;
    int c2 = t & 63;              // col pair 2*c2, 2*c2+1
    int qu = t >> 6;              // row strand 0..3

    int lo = 0, hi = NN;
    while (lo < hi) { int mid = (lo + hi) >> 1; if (batch[mid] < g) lo = mid + 1; else hi = mid; }
    int start = lo;
    hi = NN;
    while (lo < hi) { int mid = (lo + hi) >> 1; if (batch[mid] < g + 1) lo = mid + 1; else hi = mid; }
    int end = lo;

    float ax = 0.f, ay = 0.f;
    for (int i = start + qu; i < end; i += 4) {
        unsigned u = *reinterpret_cast<const unsigned*>(h + (size_t)i * DD + c2 * 2);
        ax += bflo(u); ay += bfhi(u);
    }

    __shared__ float ps[4][DD];
    ps[qu][c2 * 2] = ax;
    ps[qu][c2 * 2 + 1] = ay;
    __syncthreads();
    if (t < DD) {
        float inv = 1.0f / fmaxf((float)(end - start), 1.0f);
        ps[0][t] = (ps[0][t] + ps[1][t] + ps[2][t] + ps[3][t]) * inv;
    }
    __syncthreads();
    if (t < DD) {
        float o = b[t];
        #pragma unroll 8
        for (int k = 0; k < DD; ++k)
            o += ps[0][k] * W[k * DD + t];
        out[(size_t)g * DD + t] = fmaxf(o, 0.f);
    }
}

extern "C" void kernel_launch(void* const* d_in, const int* in_sizes, int n_in,
                              void* d_out, int out_size, void* d_ws, size_t ws_size,
                              hipStream_t stream) {
    const float* x     = (const float*)d_in[0];
    const int*   ei    = (const int*)d_in[1];
    const int*   batch = (const int*)d_in[2];
    const float* W1    = (const float*)d_in[3];
    const float* b1    = (const float*)d_in[4];
    const float* W2    = (const float*)d_in[5];
    const float* b2    = (const float*)d_in[6];
    const float* gamma = (const float*)d_in[7];
    const float* beta  = (const float*)d_in[8];
    const float* rmean = (const float*)d_in[9];
    const float* rvar  = (const float*)d_in[10];
    const float* eps   = (const float*)d_in[11];
    const float* lin1W = (const float*)d_in[12];
    const float* lin1b = (const float*)d_in[13];
    float* out = (float*)d_out;

    char* ws = (char*)d_ws;
    size_t off = 0;
    auto alloc = [&](size_t bytes) {
        void* p = ws + off;
        off = (off + bytes + 255) & ~(size_t)255;
        return p;
    };
    unsigned short* h0  = (unsigned short*)alloc((size_t)(NN + 1) * DD * 2);
    unsigned short* h1  = (unsigned short*)alloc((size_t)(NN + 1) * DD * 2);
    int* rp      = (int*)alloc((size_t)(NN + 1) * 4);
    int* blkhist = (int*)alloc((size_t)NBUCK2 * ABLKS * 4);
    int* bsumb   = (int*)alloc((size_t)NBUCK2 * 4);
    int* cboff   = (int*)alloc((size_t)(NBUCK2 + 1) * 4);
    int* bsum    = (int*)alloc((size_t)NBUCK2 * 4);
    int* bbase   = (int*)alloc((size_t)NBUCK2 * 4);
    int* csr     = (int*)alloc((size_t)CSRP * 4);
    int* ebuf    = (int*)alloc((size_t)NE * 4);
    unsigned short* wbf = (unsigned short*)alloc((size_t)NL * 2 * DD * DD * 2);

    init_all<<<INIT_BLKS, 256, 0, stream>>>(x, h0, h1, W1, W2, wbf, ei, blkhist);
    scanA<<<NBUCK2, 256, 0, stream>>>(blkhist, bsumb);
    scanB<<<1, 256, 0, stream>>>(bsumb, cboff);
    binA2<<<ABLKS, 256, 0, stream>>>(ei, cboff, blkhist, ebuf);
    bpre<<<NBUCK2, 256, 0, stream>>>(ebuf, cboff, rp, bsum);
    bscan2<<<1, 256, 0, stream>>>(bsum, bbase, rp);
    binB2<<<NBUCK2, 256, 0, stream>>>(ebuf, cboff, bbase, rp, csr);

    const int lgrid = NN / 16;   // 6250, exact
    layer_fused<<<lgrid, 256, 0, stream>>>(
        h0, rp, csr, wbf + 0 * DD * DD, wbf + 1 * DD * DD,
        b1 + 0 * DD, b2 + 0 * DD, gamma + 0 * DD, beta + 0 * DD,
        rmean + 0 * DD, rvar + 0 * DD, eps + 0, h1);
    layer_fused<<<lgrid, 256, 0, stream>>>(
        h1, rp, csr, wbf + 2 * DD * DD, wbf + 3 * DD * DD,
        b1 + 1 * DD, b2 + 1 * DD, gamma + 1 * DD, beta + 1 * DD,
        rmean + 1 * DD, rvar + 1 * DD, eps + 1, h0);
    layer_fused<<<lgrid, 256, 0, stream>>>(
        h0, rp, csr, wbf + 4 * DD * DD, wbf + 5 * DD * DD,
        b1 + 2 * DD, b2 + 2 * DD, gamma + 2 * DD, beta + 2 * DD,
        rmean + 2 * DD, rvar + 2 * DD, eps + 2, h1);

    pool_final<<<NG, 256, 0, stream>>>(h1, batch, lin1W, lin1b, out);
}